// Round 15
// baseline (91.719 us; speedup 1.0000x reference)
//
#include <hip/hip_runtime.h>
#include <stdint.h>

typedef float f32x4 __attribute__((ext_vector_type(4)));
typedef unsigned short u16x4 __attribute__((ext_vector_type(4)));
typedef unsigned short u16x8 __attribute__((ext_vector_type(8)));
typedef __bf16 bf16x8 __attribute__((ext_vector_type(8)));

// ---------- helpers ----------
__device__ __forceinline__ unsigned short f2bf(float f) {
  unsigned u = __float_as_uint(f);
  u += 0x7fffu + ((u >> 16) & 1u);   // RNE; inputs finite
  return (unsigned short)(u >> 16);
}
__device__ __forceinline__ float bf2f(unsigned short h) {
  return __uint_as_float(((unsigned)h) << 16);
}
__device__ __forceinline__ f32x4 mfma16x16x32(u16x8 a, u16x8 b, f32x4 c) {
  return __builtin_amdgcn_mfma_f32_16x16x32_bf16(
      __builtin_bit_cast(bf16x8, a), __builtin_bit_cast(bf16x8, b), c, 0, 0, 0);
}
__device__ __forceinline__ void gload_lds16(const unsigned short* g, unsigned short* l) {
  __builtin_amdgcn_global_load_lds((__attribute__((address_space(1))) void*)(g),
                                   (__attribute__((address_space(3))) void*)(l), 16, 0, 0);
}
// XCD-aware bijective remap (grid % 8 == 0): contiguous logical chunk per XCD.
__device__ __forceinline__ int xcd_swz(int bid, int nb) {
  int cpx = nb >> 3;
  return (bid & 7) * cpx + (bid >> 3);
}
// tanh-form GELU via HW exp: max |err| ~3e-3 vs exact erf-GELU (threshold 0.104)
__device__ __forceinline__ float gelu_f(float v) {
  float z = 0.7978845608f * (v + 0.044715f * v * v * v);
  float t = __expf(-2.0f * z);
  return v * (1.0f / (1.0f + t));    // 0.5v(1+tanh z) = v*sigmoid(2z)
}

// ---------- prep: wq fp32->bf16 cast (blocks 0..767) + LN1 + x->bf16 (768..1791) ----------
__global__ __launch_bounds__(256)
void prep(const float* __restrict__ wq, unsigned short* __restrict__ dst,
          const float* __restrict__ x, const float* __restrict__ nw,
          const float* __restrict__ nb, unsigned short* __restrict__ hout,
          unsigned short* __restrict__ xbf) {
  if (blockIdx.x < 768) {
    int e = (blockIdx.x * 256 + threadIdx.x) << 2;
    f32x4 v = *(const f32x4*)(wq + e);
    u16x4 o;
    #pragma unroll
    for (int i = 0; i < 4; ++i) o[i] = f2bf(v[i]);
    *(u16x4*)(dst + e) = o;
  } else {
    const int row = ((blockIdx.x - 768) << 2) + (threadIdx.x >> 6);
    const int lane = threadIdx.x & 63;
    const float* xr = x + (size_t)row * 512 + (lane << 3);
    f32x4 v0 = *(const f32x4*)xr;
    f32x4 v1 = *(const f32x4*)(xr + 4);
    float s = 0.f, s2 = 0.f;
    #pragma unroll
    for (int i = 0; i < 4; ++i) { s += v0[i] + v1[i]; s2 += v0[i]*v0[i] + v1[i]*v1[i]; }
    #pragma unroll
    for (int m = 1; m < 64; m <<= 1) { s += __shfl_xor(s, m); s2 += __shfl_xor(s2, m); }
    float mean = s * (1.0f / 512.0f);
    float var  = s2 * (1.0f / 512.0f) - mean * mean;
    float rs = rsqrtf(var + 1e-5f);
    const int d = lane << 3;
    u16x8 o, xo;
    #pragma unroll
    for (int i = 0; i < 8; ++i) {
      float xv = (i < 4) ? v0[i] : v1[i - 4];
      xo[i] = f2bf(xv);
      o[i] = f2bf((xv - mean) * rs * nw[d + i] + nb[d + i]);
    }
    *(u16x8*)(hout + (size_t)row * 512 + d) = o;
    *(u16x8*)(xbf  + (size_t)row * 512 + d) = xo;
  }
}

// ---------- LayerNorm (bf16 in) -> bf16 out ----------
__global__ __launch_bounds__(256)
void ln_bf16b(const unsigned short* __restrict__ x, const float* __restrict__ w,
              const float* __restrict__ b, unsigned short* __restrict__ out) {
  const int row = (blockIdx.x << 2) + (threadIdx.x >> 6);
  const int lane = threadIdx.x & 63;
  u16x8 xv = *(const u16x8*)(x + (size_t)row * 512 + (lane << 3));
  float f[8];
  float s = 0.f, s2 = 0.f;
  #pragma unroll
  for (int i = 0; i < 8; ++i) { f[i] = bf2f(xv[i]); s += f[i]; s2 += f[i]*f[i]; }
  #pragma unroll
  for (int m = 1; m < 64; m <<= 1) { s += __shfl_xor(s, m); s2 += __shfl_xor(s2, m); }
  float mean = s * (1.0f / 512.0f);
  float var  = s2 * (1.0f / 512.0f) - mean * mean;
  float rs = rsqrtf(var + 1e-5f);
  const int d = lane << 3;
  u16x8 o;
  #pragma unroll
  for (int i = 0; i < 8; ++i)
    o[i] = f2bf((f[i] - mean) * rs * w[d + i] + b[d + i]);
  *(u16x8*)(out + (size_t)row * 512 + d) = o;
}

// ---------- GEMM: C[M,N] = A[M,K](bf16,rm) * B[N,K](bf16,rm)^T + epilogue ----------
// Single-buffer LDS, swizzled. XCD-chunked block remap.
// EPI 0: +bias -> bf16                 EPI 2: +bias, GELU(tanh) -> bf16
// EPI 4: +bias +residB(bf16) -> fp32   EPI 5: +bias +residB(bf16) -> bf16
// WRV: V third (cols>=1024) goes ONLY to vt[b][par][h][d][k'] (transposed).
template<int BM, int BN, int BK, int EPI, int WRV>
__global__ __launch_bounds__(256)
void gemm_bt(const unsigned short* __restrict__ A, const unsigned short* __restrict__ B,
             const float* __restrict__ bias,
             const unsigned short* __restrict__ residB,
             float* __restrict__ Cf, unsigned short* __restrict__ Cb,
             unsigned short* __restrict__ vt,
             int M, int N, int K) {
  constexpr int AM = BM / 32, AN = BN / 32;   // per-wave 16x16 frags
  constexpr int CPR = BK / 8;                 // 16B chunks per row
  constexpr int RPI = 2048 / BK;              // rows staged per 256-chunk pass
  constexpr int LA = BM / RPI, LB = BN / RPI; // gload passes
  constexpr int XM = (CPR - 1) < 7 ? (CPR - 1) : 7;  // swizzle mask
  __shared__ __align__(16) unsigned short lA[BM * BK];
  __shared__ __align__(16) unsigned short lB[BN * BK];
  const int tid = threadIdx.x;
  const int wave = tid >> 6, lane = tid & 63;
  const int bid = xcd_swz(blockIdx.x, gridDim.x);
  const int gn = N / BN;
  const int tm = bid / gn, tn = bid - tm * gn;
  const int m0 = tm * BM, n0 = tn * BN;
  const int wr = wave >> 1, wc = wave & 1;
  const int lr = lane & 15;
  const int lk = (lane >> 4) << 3;
  const int rit  = tid / CPR;                 // row within it-pass
  const int csw  = ((tid % CPR) ^ (rit & XM)) << 3;  // swizzled source k-offset
  f32x4 acc[AM][AN] = {};
  for (int k0 = 0; k0 < K; k0 += BK) {
    #pragma unroll
    for (int it = 0; it < LA; ++it)
      gload_lds16(A + (size_t)(m0 + it * RPI + rit) * K + k0 + csw,
                  &lA[((it << 8) + (wave << 6)) << 3]);
    #pragma unroll
    for (int it = 0; it < LB; ++it)
      gload_lds16(B + (size_t)(n0 + it * RPI + rit) * K + k0 + csw,
                  &lB[((it << 8) + (wave << 6)) << 3]);
    __syncthreads();
    #pragma unroll
    for (int kk = 0; kk < BK; kk += 32) {
      u16x8 af[AM], bfv[AN];
      #pragma unroll
      for (int m = 0; m < AM; ++m) {
        int row = wr * (BM / 2) + (m << 4) + lr;
        int sc = ((((kk + lk) >> 3) ^ (lr & XM)) << 3);
        af[m] = *(const u16x8*)&lA[row * BK + sc];
      }
      #pragma unroll
      for (int n = 0; n < AN; ++n) {
        int row = wc * (BN / 2) + (n << 4) + lr;
        int sc = ((((kk + lk) >> 3) ^ (lr & XM)) << 3);
        bfv[n] = *(const u16x8*)&lB[row * BK + sc];
      }
      #pragma unroll
      for (int m = 0; m < AM; ++m)
        #pragma unroll
        for (int n = 0; n < AN; ++n)
          acc[m][n] = mfma16x16x32(af[m], bfv[n], acc[m][n]);
    }
    __syncthreads();
  }
  const int rbase = m0 + wr * (BM / 2) + ((lane >> 4) << 2);
  const int cbase = n0 + wc * (BN / 2) + lr;
  #pragma unroll
  for (int m = 0; m < AM; ++m) {
    #pragma unroll
    for (int n = 0; n < AN; ++n) {
      int col = cbase + (n << 4);
      float bcol = bias[col];
      #pragma unroll
      for (int i = 0; i < 4; ++i) {
        int row = rbase + (m << 4) + i;
        float v = acc[m][n][i] + bcol;
        size_t off = (size_t)row * N + col;
        if (WRV && col >= 1024) {   // V third -> ONLY transposed vt[b][par][h][d][k']
          int hh = (col - 1024) >> 6, dd = (col - 1024) & 63;
          int bb = row >> 11, tok = row & 2047;
          long long vrow = ((((((long long)bb << 1) + (tok & 1)) << 3) + hh) << 6) + dd;
          vt[(vrow << 10) + (tok >> 1)] = f2bf(v);
        } else if (EPI == 0) {
          Cb[off] = f2bf(v);
        } else if (EPI == 2) {
          Cb[off] = f2bf(gelu_f(v));
        } else if (EPI == 5) {
          Cb[off] = f2bf(v + bf2f(residB[off]));
        } else {
          Cf[off] = v + bf2f(residB[off]);
        }
      }
    }
  }
}

// ---------- MFMA dilated windowed causal attention (barrier-free) ----------
// Blocks 0..511: attention. Blocks 512+: wo/w1/w2 fp32->bf16 streaming cast
// (fills idle issue slots of the latency-bound attn blocks; results consumed
// only by LATER kernels, so the kernel boundary orders them).
__global__ __launch_bounds__(256)
void attn_mfma(const unsigned short* __restrict__ qkv,
               const unsigned short* __restrict__ vt,
               unsigned short* __restrict__ out,
               const float* __restrict__ wo, const float* __restrict__ w1,
               const float* __restrict__ w2, unsigned short* __restrict__ wdst) {
  if (blockIdx.x >= 512) {
    int e = ((blockIdx.x - 512) * 256 + threadIdx.x) << 2;   // 0..2359296
    const float* src; int off;
    if (e < 262144)        { src = wo; off = 0; }
    else if (e < 1310720)  { src = w1; off = 262144; }
    else                   { src = w2; off = 1310720; }
    f32x4 v = *(const f32x4*)(src + e - off);
    u16x4 o;
    #pragma unroll
    for (int i = 0; i < 4; ++i) o[i] = f2bf(v[i]);
    *(u16x4*)(wdst + 786432 + e) = o;
    return;
  }
  __shared__ __align__(16) unsigned short Pl[4][16 * 168];   // per-wave P: [q][k], ld=168
  const int bid = xcd_swz(blockIdx.x, 512);
  const int qt  = bid & 15;
  const int par = (bid >> 4) & 1;
  const int h   = (bid >> 5) & 7;
  const int b   = bid >> 8;
  const int q0  = qt << 6;
  const int tid = threadIdx.x, wave = tid >> 6, lane = tid & 63;

  const int col = lane & 15;
  const int rg  = lane >> 4;
  const int qt0 = q0 + (wave << 4);
  unsigned short* Pw = Pl[wave];

  const long long qrow = (long long)((b << 11) + ((qt0 + col) << 1) + par);
  const unsigned short* qp = qkv + qrow * 1536 + (h << 6) + (rg << 3);
  u16x8 qa0 = *(const u16x8*)(qp);
  u16x8 qa1 = *(const u16x8*)(qp + 32);

  f32x4 sc[9];
  #pragma unroll
  for (int j = 0; j < 9; ++j) sc[j] = (f32x4){0.f, 0.f, 0.f, 0.f};
  #pragma unroll
  for (int j = 0; j < 9; ++j) {
    int kpj = qt0 - 128 + (j << 4) + col;
    long long krow = (long long)((b << 11) + (kpj << 1) + par);
    const unsigned short* kp = qkv + krow * 1536 + 512 + (h << 6) + (rg << 3);
    u16x8 k0 = *(const u16x8*)(kp);
    u16x8 k1 = *(const u16x8*)(kp + 32);
    sc[j] = mfma16x16x32(qa0, k0, sc[j]);
    sc[j] = mfma16x16x32(qa1, k1, sc[j]);
  }

  // V prefetch (independent of softmax) — issues now, consumed after softmax
  const long long vbase = ((long long)((((b << 1) + par) << 3) + h)) << 16;
  u16x8 vb[5][4];
  #pragma unroll
  for (int ks = 0; ks < 5; ++ks) {
    long long kp0 = (long long)qt0 - 128 + (ks << 5) + (rg << 3);
    #pragma unroll
    for (int n = 0; n < 4; ++n)
      vb[ks][n] = *(const u16x8*)(vt + vbase + (((long long)((n << 4) + col)) << 10) + kp0);
  }

  float mrow[4] = {-3e38f, -3e38f, -3e38f, -3e38f};
  #pragma unroll
  for (int j = 0; j < 9; ++j) {
    #pragma unroll
    for (int i = 0; i < 4; ++i) {
      int qr = (rg << 2) + i;
      int jk = (j << 4) + col;
      bool ok = (jk >= qr) && (jk <= qr + 128) && (qt0 + jk >= 128);
      float s = ok ? sc[j][i] * 0.125f : -1e30f;
      sc[j][i] = s;
      mrow[i] = fmaxf(mrow[i], s);
    }
  }
  #pragma unroll
  for (int i = 0; i < 4; ++i)
    #pragma unroll
    for (int m = 1; m < 16; m <<= 1) mrow[i] = fmaxf(mrow[i], __shfl_xor(mrow[i], m));

  float lrow[4] = {0.f, 0.f, 0.f, 0.f};
  #pragma unroll
  for (int j = 0; j < 9; ++j) {
    #pragma unroll
    for (int i = 0; i < 4; ++i) {
      float p = __expf(sc[j][i] - mrow[i]);
      lrow[i] += p;
      Pw[((rg << 2) + i) * 168 + (j << 4) + col] = f2bf(p);
    }
  }
  #pragma unroll
  for (int i = 0; i < 4; ++i)
    Pw[((rg << 2) + i) * 168 + 144 + col] = 0;
  #pragma unroll
  for (int i = 0; i < 4; ++i)
    #pragma unroll
    for (int m = 1; m < 16; m <<= 1) lrow[i] += __shfl_xor(lrow[i], m);
  float inv[4];
  #pragma unroll
  for (int i = 0; i < 4; ++i) inv[i] = 1.0f / lrow[i];

  f32x4 oacc[4] = {};
  #pragma unroll
  for (int ks = 0; ks < 5; ++ks) {
    u16x8 pa = *(const u16x8*)&Pw[col * 168 + (ks << 5) + (rg << 3)];
    #pragma unroll
    for (int n = 0; n < 4; ++n)
      oacc[n] = mfma16x16x32(pa, vb[ks][n], oacc[n]);
  }

  #pragma unroll
  for (int n = 0; n < 4; ++n) {
    #pragma unroll
    for (int i = 0; i < 4; ++i) {
      int q = qt0 + (rg << 2) + i;
      size_t off = ((size_t)((b << 11) + (q << 1) + par)) * 512 + (h << 6) + (n << 4) + col;
      out[off] = f2bf(oacc[n][i] * inv[i]);
    }
  }
}

// ---------- launch ----------
extern "C" void kernel_launch(void* const* d_in, const int* in_sizes, int n_in,
                              void* d_out, int out_size, void* d_ws, size_t ws_size,
                              hipStream_t stream) {
  const float* x     = (const float*)d_in[0];
  const float* n1w   = (const float*)d_in[1];
  const float* n1b   = (const float*)d_in[2];
  const float* qkv_w = (const float*)d_in[3];
  const float* qkv_b = (const float*)d_in[4];
  const float* out_w = (const float*)d_in[5];
  const float* out_b = (const float*)d_in[6];
  const float* n2w   = (const float*)d_in[7];
  const float* n2b   = (const float*)d_in[8];
  const float* w1    = (const float*)d_in[9];
  const float* b1    = (const float*)d_in[10];
  const float* w2    = (const float*)d_in[11];
  const float* b2    = (const float*)d_in[12];

  char* ws = (char*)d_ws;
  unsigned short* wbf   = (unsigned short*)(ws);
  unsigned short* wq_bf = wbf;                              // [1536,512]
  unsigned short* wo_bf = (unsigned short*)(ws + 1572864);  // [512,512]
  unsigned short* w1_bf = (unsigned short*)(ws + 2097152);  // [2048,512]
  unsigned short* w2_bf = (unsigned short*)(ws + 4194304);  // [512,2048]
  unsigned short* h_bf  = (unsigned short*)(ws + 6291456);  // [4096,512]
  unsigned short* qkvb  = (unsigned short*)(ws + 10485760); // [4096,1536] bf16
  unsigned short* ao_bf = (unsigned short*)(ws + 23068672); // [4096,512] bf16
  unsigned short* x1r   = (unsigned short*)(ws + 27262976); // [4096,512] bf16 residual
  unsigned short* f1_bf = (unsigned short*)(ws + 10485760); // [4096,2048] aliases dead qkv+ao
  unsigned short* vt    = (unsigned short*)(ws + 35651584); // [2,2,8,64,1024] V^T bf16, 4MB
  unsigned short* xbf   = (unsigned short*)(ws + 44040192); // [4096,512] bf16 copy of x
  float* outp = (float*)d_out;

  prep<<<1792, 256, 0, stream>>>(qkv_w, wbf, x, n1w, n1b, h_bf, xbf);
  gemm_bt<128, 64, 128, 0, 1><<<32 * 24, 256, 0, stream>>>(
      h_bf, wq_bf, qkv_b, nullptr, nullptr, qkvb, vt, 4096, 1536, 512);
  attn_mfma<<<512 + 2304, 256, 0, stream>>>(qkvb, vt, ao_bf, out_w, w1, w2, wbf);
  gemm_bt<32, 64, 128, 5, 0><<<128 * 8, 256, 0, stream>>>(
      ao_bf, wo_bf, out_b, xbf, nullptr, x1r, nullptr, 4096, 512, 512);
  ln_bf16b<<<1024, 256, 0, stream>>>(x1r, n2w, n2b, h_bf);
  gemm_bt<128, 128, 128, 2, 0><<<32 * 16, 256, 0, stream>>>(
      h_bf, w1_bf, b1, nullptr, nullptr, f1_bf, nullptr, 4096, 2048, 512);
  gemm_bt<32, 64, 256, 4, 0><<<128 * 8, 256, 0, stream>>>(
      f1_bf, w2_bf, b2, x1r, outp, nullptr, nullptr, 4096, 512, 2048);
}

// Round 16
// 83.712 us; speedup vs baseline: 1.0956x; 1.0956x over previous
//
#include <hip/hip_runtime.h>
#include <stdint.h>

typedef float f32x4 __attribute__((ext_vector_type(4)));
typedef unsigned short u16x4 __attribute__((ext_vector_type(4)));
typedef unsigned short u16x8 __attribute__((ext_vector_type(8)));
typedef __bf16 bf16x8 __attribute__((ext_vector_type(8)));

// ---------- helpers ----------
__device__ __forceinline__ unsigned short f2bf(float f) {
  unsigned u = __float_as_uint(f);
  u += 0x7fffu + ((u >> 16) & 1u);   // RNE; inputs finite
  return (unsigned short)(u >> 16);
}
__device__ __forceinline__ float bf2f(unsigned short h) {
  return __uint_as_float(((unsigned)h) << 16);
}
__device__ __forceinline__ f32x4 mfma16x16x32(u16x8 a, u16x8 b, f32x4 c) {
  return __builtin_amdgcn_mfma_f32_16x16x32_bf16(
      __builtin_bit_cast(bf16x8, a), __builtin_bit_cast(bf16x8, b), c, 0, 0, 0);
}
__device__ __forceinline__ void gload_lds16(const unsigned short* g, unsigned short* l) {
  __builtin_amdgcn_global_load_lds((__attribute__((address_space(1))) void*)(g),
                                   (__attribute__((address_space(3))) void*)(l), 16, 0, 0);
}
// XCD-aware bijective remap (grid % 8 == 0): contiguous logical chunk per XCD.
__device__ __forceinline__ int xcd_swz(int bid, int nb) {
  int cpx = nb >> 3;
  return (bid & 7) * cpx + (bid >> 3);
}
// tanh-form GELU via HW exp: max |err| ~3e-3 vs exact erf-GELU (threshold 0.104)
__device__ __forceinline__ float gelu_f(float v) {
  float z = 0.7978845608f * (v + 0.044715f * v * v * v);
  float t = __expf(-2.0f * z);
  return v * (1.0f / (1.0f + t));    // 0.5v(1+tanh z) = v*sigmoid(2z)
}

// ---------- prep: wq fp32->bf16 cast (blocks 0..767) + LN1 + x->bf16 (768..1791) ----------
__global__ __launch_bounds__(256)
void prep(const float* __restrict__ wq, unsigned short* __restrict__ dst,
          const float* __restrict__ x, const float* __restrict__ nw,
          const float* __restrict__ nb, unsigned short* __restrict__ hout,
          unsigned short* __restrict__ xbf) {
  if (blockIdx.x < 768) {
    int e = (blockIdx.x * 256 + threadIdx.x) << 2;
    f32x4 v = *(const f32x4*)(wq + e);
    u16x4 o;
    #pragma unroll
    for (int i = 0; i < 4; ++i) o[i] = f2bf(v[i]);
    *(u16x4*)(dst + e) = o;
  } else {
    const int row = ((blockIdx.x - 768) << 2) + (threadIdx.x >> 6);
    const int lane = threadIdx.x & 63;
    const float* xr = x + (size_t)row * 512 + (lane << 3);
    f32x4 v0 = *(const f32x4*)xr;
    f32x4 v1 = *(const f32x4*)(xr + 4);
    float s = 0.f, s2 = 0.f;
    #pragma unroll
    for (int i = 0; i < 4; ++i) { s += v0[i] + v1[i]; s2 += v0[i]*v0[i] + v1[i]*v1[i]; }
    #pragma unroll
    for (int m = 1; m < 64; m <<= 1) { s += __shfl_xor(s, m); s2 += __shfl_xor(s2, m); }
    float mean = s * (1.0f / 512.0f);
    float var  = s2 * (1.0f / 512.0f) - mean * mean;
    float rs = rsqrtf(var + 1e-5f);
    const int d = lane << 3;
    u16x8 o, xo;
    #pragma unroll
    for (int i = 0; i < 8; ++i) {
      float xv = (i < 4) ? v0[i] : v1[i - 4];
      xo[i] = f2bf(xv);
      o[i] = f2bf((xv - mean) * rs * nw[d + i] + nb[d + i]);
    }
    *(u16x8*)(hout + (size_t)row * 512 + d) = o;
    *(u16x8*)(xbf  + (size_t)row * 512 + d) = xo;
  }
}

// ---------- LayerNorm (bf16 in) -> bf16 out ----------
__global__ __launch_bounds__(256)
void ln_bf16b(const unsigned short* __restrict__ x, const float* __restrict__ w,
              const float* __restrict__ b, unsigned short* __restrict__ out) {
  const int row = (blockIdx.x << 2) + (threadIdx.x >> 6);
  const int lane = threadIdx.x & 63;
  u16x8 xv = *(const u16x8*)(x + (size_t)row * 512 + (lane << 3));
  float f[8];
  float s = 0.f, s2 = 0.f;
  #pragma unroll
  for (int i = 0; i < 8; ++i) { f[i] = bf2f(xv[i]); s += f[i]; s2 += f[i]*f[i]; }
  #pragma unroll
  for (int m = 1; m < 64; m <<= 1) { s += __shfl_xor(s, m); s2 += __shfl_xor(s2, m); }
  float mean = s * (1.0f / 512.0f);
  float var  = s2 * (1.0f / 512.0f) - mean * mean;
  float rs = rsqrtf(var + 1e-5f);
  const int d = lane << 3;
  u16x8 o;
  #pragma unroll
  for (int i = 0; i < 8; ++i)
    o[i] = f2bf((f[i] - mean) * rs * w[d + i] + b[d + i]);
  *(u16x8*)(out + (size_t)row * 512 + d) = o;
}

// ---------- GEMM: C[M,N] = A[M,K](bf16,rm) * B[N,K](bf16,rm)^T + epilogue ----------
// Single-buffer LDS, swizzled. XCD-chunked block remap.
// EPI 0: +bias -> bf16                 EPI 2: +bias, GELU(tanh) -> bf16
// EPI 4: +bias +residB(bf16) -> fp32   EPI 5: +bias +residB(bf16) -> bf16
// WRV: V third (cols>=1024) goes ONLY to vt[b][par][h][d][k'] (transposed).
template<int BM, int BN, int BK, int EPI, int WRV>
__global__ __launch_bounds__(256)
void gemm_bt(const unsigned short* __restrict__ A, const unsigned short* __restrict__ B,
             const float* __restrict__ bias,
             const unsigned short* __restrict__ residB,
             float* __restrict__ Cf, unsigned short* __restrict__ Cb,
             unsigned short* __restrict__ vt,
             int M, int N, int K) {
  constexpr int AM = BM / 32, AN = BN / 32;   // per-wave 16x16 frags
  constexpr int CPR = BK / 8;                 // 16B chunks per row
  constexpr int RPI = 2048 / BK;              // rows staged per 256-chunk pass
  constexpr int LA = BM / RPI, LB = BN / RPI; // gload passes
  constexpr int XM = (CPR - 1) < 7 ? (CPR - 1) : 7;  // swizzle mask
  __shared__ __align__(16) unsigned short lA[BM * BK];
  __shared__ __align__(16) unsigned short lB[BN * BK];
  const int tid = threadIdx.x;
  const int wave = tid >> 6, lane = tid & 63;
  const int bid = xcd_swz(blockIdx.x, gridDim.x);
  const int gn = N / BN;
  const int tm = bid / gn, tn = bid - tm * gn;
  const int m0 = tm * BM, n0 = tn * BN;
  const int wr = wave >> 1, wc = wave & 1;
  const int lr = lane & 15;
  const int lk = (lane >> 4) << 3;
  const int rit  = tid / CPR;                 // row within it-pass
  const int csw  = ((tid % CPR) ^ (rit & XM)) << 3;  // swizzled source k-offset
  f32x4 acc[AM][AN] = {};
  for (int k0 = 0; k0 < K; k0 += BK) {
    #pragma unroll
    for (int it = 0; it < LA; ++it)
      gload_lds16(A + (size_t)(m0 + it * RPI + rit) * K + k0 + csw,
                  &lA[((it << 8) + (wave << 6)) << 3]);
    #pragma unroll
    for (int it = 0; it < LB; ++it)
      gload_lds16(B + (size_t)(n0 + it * RPI + rit) * K + k0 + csw,
                  &lB[((it << 8) + (wave << 6)) << 3]);
    __syncthreads();
    #pragma unroll
    for (int kk = 0; kk < BK; kk += 32) {
      u16x8 af[AM], bfv[AN];
      #pragma unroll
      for (int m = 0; m < AM; ++m) {
        int row = wr * (BM / 2) + (m << 4) + lr;
        int sc = ((((kk + lk) >> 3) ^ (lr & XM)) << 3);
        af[m] = *(const u16x8*)&lA[row * BK + sc];
      }
      #pragma unroll
      for (int n = 0; n < AN; ++n) {
        int row = wc * (BN / 2) + (n << 4) + lr;
        int sc = ((((kk + lk) >> 3) ^ (lr & XM)) << 3);
        bfv[n] = *(const u16x8*)&lB[row * BK + sc];
      }
      #pragma unroll
      for (int m = 0; m < AM; ++m)
        #pragma unroll
        for (int n = 0; n < AN; ++n)
          acc[m][n] = mfma16x16x32(af[m], bfv[n], acc[m][n]);
    }
    __syncthreads();
  }
  const int rbase = m0 + wr * (BM / 2) + ((lane >> 4) << 2);
  const int cbase = n0 + wc * (BN / 2) + lr;
  #pragma unroll
  for (int m = 0; m < AM; ++m) {
    #pragma unroll
    for (int n = 0; n < AN; ++n) {
      int col = cbase + (n << 4);
      float bcol = bias[col];
      #pragma unroll
      for (int i = 0; i < 4; ++i) {
        int row = rbase + (m << 4) + i;
        float v = acc[m][n][i] + bcol;
        size_t off = (size_t)row * N + col;
        if (WRV && col >= 1024) {   // V third -> ONLY transposed vt[b][par][h][d][k']
          int hh = (col - 1024) >> 6, dd = (col - 1024) & 63;
          int bb = row >> 11, tok = row & 2047;
          long long vrow = ((((((long long)bb << 1) + (tok & 1)) << 3) + hh) << 6) + dd;
          vt[(vrow << 10) + (tok >> 1)] = f2bf(v);
        } else if (EPI == 0) {
          Cb[off] = f2bf(v);
        } else if (EPI == 2) {
          Cb[off] = f2bf(gelu_f(v));
        } else if (EPI == 5) {
          Cb[off] = f2bf(v + bf2f(residB[off]));
        } else {
          Cf[off] = v + bf2f(residB[off]);
        }
      }
    }
  }
}

// ---------- MFMA dilated windowed causal attention (barrier-free) ----------
// Blocks 0..511: attention. Blocks 512+: wo/w1/w2 fp32->bf16 streaming cast
// (fills idle issue slots of the latency-bound attn blocks; results consumed
// only by LATER kernels, so the kernel boundary orders them).
__global__ __launch_bounds__(256)
void attn_mfma(const unsigned short* __restrict__ qkv,
               const unsigned short* __restrict__ vt,
               unsigned short* __restrict__ out,
               const float* __restrict__ wo, const float* __restrict__ w1,
               const float* __restrict__ w2, unsigned short* __restrict__ wdst) {
  if (blockIdx.x >= 512) {
    int e = ((blockIdx.x - 512) * 256 + threadIdx.x) << 2;   // 0..2359296
    const float* src; int off;
    if (e < 262144)        { src = wo; off = 0; }
    else if (e < 1310720)  { src = w1; off = 262144; }
    else                   { src = w2; off = 1310720; }
    f32x4 v = *(const f32x4*)(src + e - off);
    u16x4 o;
    #pragma unroll
    for (int i = 0; i < 4; ++i) o[i] = f2bf(v[i]);
    *(u16x4*)(wdst + 786432 + e) = o;
    return;
  }
  __shared__ __align__(16) unsigned short Pl[4][16 * 168];   // per-wave P: [q][k], ld=168
  const int bid = xcd_swz(blockIdx.x, 512);
  const int qt  = bid & 15;
  const int par = (bid >> 4) & 1;
  const int h   = (bid >> 5) & 7;
  const int b   = bid >> 8;
  const int q0  = qt << 6;
  const int tid = threadIdx.x, wave = tid >> 6, lane = tid & 63;

  const int col = lane & 15;
  const int rg  = lane >> 4;
  const int qt0 = q0 + (wave << 4);
  unsigned short* Pw = Pl[wave];

  const long long qrow = (long long)((b << 11) + ((qt0 + col) << 1) + par);
  const unsigned short* qp = qkv + qrow * 1536 + (h << 6) + (rg << 3);
  u16x8 qa0 = *(const u16x8*)(qp);
  u16x8 qa1 = *(const u16x8*)(qp + 32);

  f32x4 sc[9];
  #pragma unroll
  for (int j = 0; j < 9; ++j) sc[j] = (f32x4){0.f, 0.f, 0.f, 0.f};
  #pragma unroll
  for (int j = 0; j < 9; ++j) {
    int kpj = qt0 - 128 + (j << 4) + col;
    long long krow = (long long)((b << 11) + (kpj << 1) + par);
    const unsigned short* kp = qkv + krow * 1536 + 512 + (h << 6) + (rg << 3);
    u16x8 k0 = *(const u16x8*)(kp);
    u16x8 k1 = *(const u16x8*)(kp + 32);
    sc[j] = mfma16x16x32(qa0, k0, sc[j]);
    sc[j] = mfma16x16x32(qa1, k1, sc[j]);
  }

  // V prefetch (independent of softmax) — issues now, consumed after softmax
  const long long vbase = ((long long)((((b << 1) + par) << 3) + h)) << 16;
  u16x8 vb[5][4];
  #pragma unroll
  for (int ks = 0; ks < 5; ++ks) {
    long long kp0 = (long long)qt0 - 128 + (ks << 5) + (rg << 3);
    #pragma unroll
    for (int n = 0; n < 4; ++n)
      vb[ks][n] = *(const u16x8*)(vt + vbase + (((long long)((n << 4) + col)) << 10) + kp0);
  }

  float mrow[4] = {-3e38f, -3e38f, -3e38f, -3e38f};
  #pragma unroll
  for (int j = 0; j < 9; ++j) {
    #pragma unroll
    for (int i = 0; i < 4; ++i) {
      int qr = (rg << 2) + i;
      int jk = (j << 4) + col;
      bool ok = (jk >= qr) && (jk <= qr + 128) && (qt0 + jk >= 128);
      float s = ok ? sc[j][i] * 0.125f : -1e30f;
      sc[j][i] = s;
      mrow[i] = fmaxf(mrow[i], s);
    }
  }
  #pragma unroll
  for (int i = 0; i < 4; ++i)
    #pragma unroll
    for (int m = 1; m < 16; m <<= 1) mrow[i] = fmaxf(mrow[i], __shfl_xor(mrow[i], m));

  float lrow[4] = {0.f, 0.f, 0.f, 0.f};
  #pragma unroll
  for (int j = 0; j < 9; ++j) {
    #pragma unroll
    for (int i = 0; i < 4; ++i) {
      float p = __expf(sc[j][i] - mrow[i]);
      lrow[i] += p;
      Pw[((rg << 2) + i) * 168 + (j << 4) + col] = f2bf(p);
    }
  }
  #pragma unroll
  for (int i = 0; i < 4; ++i)
    Pw[((rg << 2) + i) * 168 + 144 + col] = 0;
  #pragma unroll
  for (int i = 0; i < 4; ++i)
    #pragma unroll
    for (int m = 1; m < 16; m <<= 1) lrow[i] += __shfl_xor(lrow[i], m);
  float inv[4];
  #pragma unroll
  for (int i = 0; i < 4; ++i) inv[i] = 1.0f / lrow[i];

  f32x4 oacc[4] = {};
  #pragma unroll
  for (int ks = 0; ks < 5; ++ks) {
    u16x8 pa = *(const u16x8*)&Pw[col * 168 + (ks << 5) + (rg << 3)];
    #pragma unroll
    for (int n = 0; n < 4; ++n)
      oacc[n] = mfma16x16x32(pa, vb[ks][n], oacc[n]);
  }

  #pragma unroll
  for (int n = 0; n < 4; ++n) {
    #pragma unroll
    for (int i = 0; i < 4; ++i) {
      int q = qt0 + (rg << 2) + i;
      size_t off = ((size_t)((b << 11) + (q << 1) + par)) * 512 + (h << 6) + (n << 4) + col;
      out[off] = f2bf(oacc[n][i] * inv[i]);
    }
  }
}

// ---------- launch ----------
extern "C" void kernel_launch(void* const* d_in, const int* in_sizes, int n_in,
                              void* d_out, int out_size, void* d_ws, size_t ws_size,
                              hipStream_t stream) {
  const float* x     = (const float*)d_in[0];
  const float* n1w   = (const float*)d_in[1];
  const float* n1b   = (const float*)d_in[2];
  const float* qkv_w = (const float*)d_in[3];
  const float* qkv_b = (const float*)d_in[4];
  const float* out_w = (const float*)d_in[5];
  const float* out_b = (const float*)d_in[6];
  const float* n2w   = (const float*)d_in[7];
  const float* n2b   = (const float*)d_in[8];
  const float* w1    = (const float*)d_in[9];
  const float* b1    = (const float*)d_in[10];
  const float* w2    = (const float*)d_in[11];
  const float* b2    = (const float*)d_in[12];

  char* ws = (char*)d_ws;
  unsigned short* wbf   = (unsigned short*)(ws);
  unsigned short* wq_bf = wbf;                              // [1536,512]
  unsigned short* wo_bf = (unsigned short*)(ws + 1572864);  // [512,512]
  unsigned short* w1_bf = (unsigned short*)(ws + 2097152);  // [2048,512]
  unsigned short* w2_bf = (unsigned short*)(ws + 4194304);  // [512,2048]
  unsigned short* h_bf  = (unsigned short*)(ws + 6291456);  // [4096,512]
  unsigned short* qkvb  = (unsigned short*)(ws + 10485760); // [4096,1536] bf16
  unsigned short* ao_bf = (unsigned short*)(ws + 23068672); // [4096,512] bf16
  unsigned short* x1r   = (unsigned short*)(ws + 27262976); // [4096,512] bf16 residual
  unsigned short* f1_bf = (unsigned short*)(ws + 10485760); // [4096,2048] aliases dead qkv+ao
  unsigned short* vt    = (unsigned short*)(ws + 35651584); // [2,2,8,64,1024] V^T bf16, 4MB
  unsigned short* xbf   = (unsigned short*)(ws + 44040192); // [4096,512] bf16 copy of x
  float* outp = (float*)d_out;

  prep<<<1792, 256, 0, stream>>>(qkv_w, wbf, x, n1w, n1b, h_bf, xbf);
  gemm_bt<128, 64, 128, 0, 1><<<32 * 24, 256, 0, stream>>>(
      h_bf, wq_bf, qkv_b, nullptr, nullptr, qkvb, vt, 4096, 1536, 512);
  attn_mfma<<<512 + 2304, 256, 0, stream>>>(qkvb, vt, ao_bf, out_w, w1, w2, wbf);
  gemm_bt<64, 64, 256, 5, 0><<<64 * 8, 256, 0, stream>>>(
      ao_bf, wo_bf, out_b, xbf, nullptr, x1r, nullptr, 4096, 512, 512);
  ln_bf16b<<<1024, 256, 0, stream>>>(x1r, n2w, n2b, h_bf);
  gemm_bt<128, 128, 128, 2, 0><<<32 * 16, 256, 0, stream>>>(
      h_bf, w1_bf, b1, nullptr, nullptr, f1_bf, nullptr, 4096, 2048, 512);
  gemm_bt<64, 64, 256, 4, 0><<<64 * 8, 256, 0, stream>>>(
      f1_bf, w2_bf, b2, x1r, outp, nullptr, nullptr, 4096, 512, 2048);
}